// Round 4
// baseline (435.331 us; speedup 1.0000x reference)
//
#include <hip/hip_runtime.h>

// g[b,h,w] = (1/N) * sum_n conj(H[n]) * (H[n]*x[b] - y[b,n])
//          = x[b]*(1/N)*sum_n |H[n]|^2  -  (1/N)*sum_n conj(H[n])*y[b,n]
//
// Round 9: final A/B — R8 exactly (float4, 512x256, 2 waves/SIMD, depth-2
// no-copy double-buffer) but with the NONTEMPORAL HINT REMOVED FROM LOADS.
// Theory: delivered read BW (pinned at 4.8 TB/s across R5-R8 regardless of
// occupancy/pipeline depth) = outstanding-lines x 64B / latency. If the NT
// (no-allocate) path adds per-line latency or routes around L2 queueing,
// plain loads raise the quotient. Traffic is identical either way (zero
// reuse). NT stores kept (4 MB, irrelevant) to isolate the load variable.
// If this ties R5/R8, the kernel is at the structural read-path ceiling.

typedef float f4 __attribute__((ext_vector_type(4)));

#define ACCUM(hv, v0, v1)                                   \
    do {                                                    \
        s0 += (hv).x * (hv).x + (hv).y * (hv).y;            \
        s1 += (hv).z * (hv).z + (hv).w * (hv).w;            \
        a00r += (hv).x * (v0).x + (hv).y * (v0).y;          \
        a00i += (hv).x * (v0).y - (hv).y * (v0).x;          \
        a01r += (hv).z * (v0).z + (hv).w * (v0).w;          \
        a01i += (hv).z * (v0).w - (hv).w * (v0).z;          \
        a10r += (hv).x * (v1).x + (hv).y * (v1).y;          \
        a10i += (hv).x * (v1).y - (hv).y * (v1).x;          \
        a11r += (hv).z * (v1).z + (hv).w * (v1).w;          \
        a11i += (hv).z * (v1).w - (hv).w * (v1).z;          \
    } while (0)

#define LOADG(bufH, buf0, buf1, g)                          \
    do {                                                    \
        const size_t base_ = (size_t)(g) * 4 * P;           \
        _Pragma("unroll")                                   \
        for (int j = 0; j < 4; ++j) {                       \
            bufH[j] = hp[base_ + (size_t)j * P];            \
            buf0[j] = y0[base_ + (size_t)j * P];            \
            buf1[j] = y1[base_ + (size_t)j * P];            \
        }                                                   \
    } while (0)

__global__ void __launch_bounds__(256, 2) idt_fused_kernel(
    const f4* __restrict__ H4,   // [N][P]
    const f4* __restrict__ Y4,   // [B=2][N][P]
    const f4* __restrict__ X4,   // [B=2][P]
    f4* __restrict__ O4,         // [B=2][P]
    const int* __restrict__ nbf,
    int N, int P)
{
    int p = blockIdx.x * blockDim.x + threadIdx.x;
    if (p >= P) return;

    float s0 = 0.f, s1 = 0.f;
    float a00r = 0.f, a00i = 0.f, a01r = 0.f, a01i = 0.f;  // b=0
    float a10r = 0.f, a10i = 0.f, a11r = 0.f, a11i = 0.f;  // b=1

    const f4* hp = H4 + p;
    const f4* y0 = Y4 + p;                       // b=0
    const f4* y1 = Y4 + (size_t)N * P + p;       // b=1

    const int G = N >> 2;                        // 16 groups of 4 n's

    f4 aH[4], a0[4], a1[4];                      // buffer A
    f4 bH[4], b0[4], b1[4];                      // buffer B

    LOADG(aH, a0, a1, 0);
    LOADG(bH, b0, b1, 1);

    // G is even (16). Unrolled-by-2 depth-2 pipeline, no register copies.
    for (int g = 0; g < G - 2; g += 2) {
        #pragma unroll
        for (int j = 0; j < 4; ++j) ACCUM(aH[j], a0[j], a1[j]);
        LOADG(aH, a0, a1, g + 2);

        #pragma unroll
        for (int j = 0; j < 4; ++j) ACCUM(bH[j], b0[j], b1[j]);
        LOADG(bH, b0, b1, g + 3);
    }

    #pragma unroll
    for (int j = 0; j < 4; ++j) ACCUM(aH[j], a0[j], a1[j]);
    #pragma unroll
    for (int j = 0; j < 4; ++j) ACCUM(bH[j], b0[j], b1[j]);

    float inv = 1.0f / (float)nbf[0];

    f4 x0 = X4[p];
    f4 x1 = X4[(size_t)P + p];

    f4 o0, o1;
    o0.x = (x0.x * s0 - a00r) * inv;
    o0.y = (x0.y * s0 - a00i) * inv;
    o0.z = (x0.z * s1 - a01r) * inv;
    o0.w = (x0.w * s1 - a01i) * inv;

    o1.x = (x1.x * s0 - a10r) * inv;
    o1.y = (x1.y * s0 - a10i) * inv;
    o1.z = (x1.z * s1 - a11r) * inv;
    o1.w = (x1.w * s1 - a11i) * inv;

    __builtin_nontemporal_store(o0, O4 + p);
    __builtin_nontemporal_store(o1, O4 + (size_t)P + p);
}

extern "C" void kernel_launch(void* const* d_in, const int* in_sizes, int n_in,
                              void* d_out, int out_size, void* d_ws, size_t ws_size,
                              hipStream_t stream) {
    const float* f_ipt = (const float*)d_in[0];   // [B,H,W,2]
    const float* f_y   = (const float*)d_in[1];   // [B,N,H,W,2]
    const float* Hreal = (const float*)d_in[2];   // [N,H,W,2]
    const int*   nbf   = (const int*)d_in[3];     // scalar NBFkeep

    const int B = in_sizes[1] / in_sizes[2];      // = 2
    const int N = in_sizes[1] / in_sizes[0];      // = 64
    const int P = in_sizes[0] / B / 4;            // = 131072 float4 groups per batch

    dim3 block(256);
    dim3 grid((P + block.x - 1) / block.x);       // 512 blocks
    idt_fused_kernel<<<grid, block, 0, stream>>>(
        (const f4*)Hreal, (const f4*)f_y, (const f4*)f_ipt,
        (f4*)d_out, nbf, N, P);
}